// Round 7
// baseline (109.238 us; speedup 1.0000x reference)
//
#include <hip/hip_runtime.h>
#include <hip/hip_bf16.h>

// Chamfer distance, B=4, N=M=8192, D=3, fp32.
// R6: fix R5's K-extent bug (mfma 16x16x32 has K=32: quads 2-3 read k=16..31;
// rows must be 32 bf16 wide — upper half zeros, quad>=2 fragments are zero).
// New: ONE MFMA pass computes the full distance matrix D[n][m] ~= ||p-t||^2
// (both norms inside via 3-way bf16 splits); row-min gives pred->target,
// col-min gives target->pred from the SAME tiles -> half the MFMA work.
//   A row (pred):  [-2h(3), -2l(3), -2h(3), pn1,pn2,pn3, 1,1,1, 0x17]
//   B row (targ):  [ h(3),   h(3),   l(3),  1,1,1, tn1,tn2,tn3, 0x17]
// Error ~ missing la.lb term ~1e-5 << 9.3e-4 threshold.
// ws (8 MB = proven available): packA 2MB | packB 2MB | rowpart 2MB | colpart 2MB

typedef __attribute__((ext_vector_type(8))) short short8;
typedef __attribute__((ext_vector_type(4))) float f32x4;

#define BATCH 4
#define NPTS 8192
#define TOTALQ (BATCH * NPTS)   // 32768
#define BLK 256
#define WNT 8                   // 16-row tiles per wave
#define NCHUNKS 16              // 8192 rows / (4 waves * 128 rows)
#define MSPLIT 16               // col slices
#define MRANGE 512              // cols per block
#define MT_PER (MRANGE / 16)    // 32 m-tiles per block

#define ROW_US 32               // ushorts per packed row (K=32)

__device__ __forceinline__ unsigned short f2bf(float f) {  // RTN-even
    unsigned int u = __float_as_uint(f);
    u += 0x7FFFu + ((u >> 16) & 1u);
    return (unsigned short)(u >> 16);
}
__device__ __forceinline__ float bf2f(unsigned short h) {
    return __uint_as_float(((unsigned int)h) << 16);
}
__device__ __forceinline__ unsigned int pk2(unsigned short a, unsigned short b) {
    return (unsigned int)a | ((unsigned int)b << 16);
}

__global__ __launch_bounds__(BLK) void chamfer_pack_kernel(
        const float* __restrict__ pred, const float* __restrict__ target,
        ushort* __restrict__ packA, ushort* __restrict__ packB,
        float* __restrict__ out)
{
    int i = blockIdx.x * BLK + threadIdx.x;        // 0..65535
    if (i == 0) out[0] = 0.0f;                     // reduce runs 2 nodes later
    int which = i >> 15;                           // 0 = pred->A, 1 = targ->B
    int p = i & (TOTALQ - 1);
    const float* src = which ? target : pred;
    float x = src[3 * p], y = src[3 * p + 1], z = src[3 * p + 2];

    unsigned short hx = f2bf(x), hy = f2bf(y), hz = f2bf(z);
    unsigned short lx = f2bf(x - bf2f(hx)), ly = f2bf(y - bf2f(hy)),
                   lz = f2bf(z - bf2f(hz));
    float nrm = fmaf(z, z, fmaf(y, y, x * x));
    unsigned short n1 = f2bf(nrm);
    float r1 = nrm - bf2f(n1);
    unsigned short n2 = f2bf(r1);
    unsigned short n3 = f2bf(r1 - bf2f(n2));
    const unsigned short ONE = 0x3F80;

    uint4 q0, q1;
    ushort* dst;
    if (which == 0) {
        // -2*h, -2*l exact (power-of-2 scale of a bf16 value)
        unsigned short ax = f2bf(-2.f * bf2f(hx)), ay = f2bf(-2.f * bf2f(hy)),
                       az = f2bf(-2.f * bf2f(hz));
        unsigned short cx = f2bf(-2.f * bf2f(lx)), cy = f2bf(-2.f * bf2f(ly)),
                       cz = f2bf(-2.f * bf2f(lz));
        // k0..15: [ax,ay,az, cx,cy,cz, ax,ay,az, n1,n2,n3, 1,1,1, 0]
        q0 = (uint4){ pk2(ax, ay), pk2(az, cx), pk2(cy, cz), pk2(ax, ay) };
        q1 = (uint4){ pk2(az, n1), pk2(n2, n3), pk2(ONE, ONE), pk2(ONE, 0) };
        dst = packA + (size_t)p * ROW_US;
    } else {
        // k0..15: [hx,hy,hz, hx,hy,hz, lx,ly,lz, 1,1,1, n1,n2,n3, 0]
        q0 = (uint4){ pk2(hx, hy), pk2(hz, hx), pk2(hy, hz), pk2(lx, ly) };
        q1 = (uint4){ pk2(lz, ONE), pk2(ONE, ONE), pk2(n1, n2), pk2(n3, 0) };
        dst = packB + (size_t)p * ROW_US;
    }
    uint4* d4 = (uint4*)dst;
    d4[0] = q0;  d4[1] = q1;
    d4[2] = (uint4){0, 0, 0, 0};  d4[3] = (uint4){0, 0, 0, 0};  // k16..31 = 0
}

__global__ __launch_bounds__(BLK, 4) void chamfer_mfma_kernel(
        const ushort* __restrict__ packA, const ushort* __restrict__ packB,
        float* __restrict__ rowpart, float* __restrict__ colpart)
{
    const int b   = blockIdx.x >> 4;      // NCHUNKS == 16
    const int nch = blockIdx.x & 15;
    const int ms  = blockIdx.y;
    const int w    = threadIdx.x >> 6;
    const int lane = threadIdx.x & 63;
    const int c = lane & 15, q = lane >> 4;

    __shared__ uint4  ldsb[2 * MRANGE];   // quarters 0,1 of each B row (16 KB)
    __shared__ float  colbuf[4][MRANGE];  // per-wave col minima (8 KB)

    const short8 zero8 = (short8){0, 0, 0, 0, 0, 0, 0, 0};
    const f32x4  zacc  = (f32x4){0.f, 0.f, 0.f, 0.f};

    // ---- stage B rows: two 16B quarters each (k0..7 | k8..15) ----
    for (int r = threadIdx.x; r < MRANGE; r += BLK) {
        const uint4* g = (const uint4*)(packB +
            ((size_t)b * NPTS + (size_t)ms * MRANGE + r) * ROW_US);
        ldsb[r]          = g[0];
        ldsb[MRANGE + r] = g[1];
    }

    // ---- A fragments: lane holds A row (rowbase + nt*16 + c), k = 8q..8q+7 ----
    const int rowbase = nch * 512 + w * 128;   // within batch
    short8 afrag[WNT];
    #pragma unroll
    for (int nt = 0; nt < WNT; ++nt) {
        afrag[nt] = (q < 2)
            ? *(const short8*)(packA +
                  ((size_t)b * NPTS + rowbase + nt * 16 + c) * ROW_US + 8 * q)
            : zero8;
    }

    f32x4 rowacc[WNT];
    #pragma unroll
    for (int nt = 0; nt < WNT; ++nt)
        rowacc[nt] = (f32x4){3.4e38f, 3.4e38f, 3.4e38f, 3.4e38f};

    __syncthreads();

    // ---- main loop over m-tiles ----
    #pragma unroll 2
    for (int mt = 0; mt < MT_PER; ++mt) {
        short8 bfrag = (q < 2)
            ? *(const short8*)&ldsb[q * MRANGE + mt * 16 + c]
            : zero8;
        float colmin = 3.4e38f;
        #pragma unroll
        for (int nt = 0; nt < WNT; ++nt) {
            f32x4 d = __builtin_amdgcn_mfma_f32_16x16x32_bf16(
                          afrag[nt], bfrag, zacc, 0, 0, 0);
            rowacc[nt].x = fminf(rowacc[nt].x, d.x);
            rowacc[nt].y = fminf(rowacc[nt].y, d.y);
            rowacc[nt].z = fminf(rowacc[nt].z, d.z);
            rowacc[nt].w = fminf(rowacc[nt].w, d.w);
            colmin = fminf(colmin,
                     fminf(fminf(d.x, d.y), fminf(d.z, d.w)));
        }
        // fold col-min across the 4 quads (rows), col c fixed per lane
        colmin = fminf(colmin, __shfl_xor(colmin, 16, 64));
        colmin = fminf(colmin, __shfl_xor(colmin, 32, 64));
        if (lane < 16) colbuf[w][mt * 16 + lane] = colmin;
    }

    // ---- row epilogue: fold across 16 col-lanes; store row partials ----
    // C layout: col = lane&15, row = q*4 + reg (m89)
    float* rp = rowpart + (size_t)ms * TOTALQ + (size_t)b * NPTS + rowbase;
    #pragma unroll
    for (int nt = 0; nt < WNT; ++nt) {
        f32x4 r = rowacc[nt];
        #pragma unroll
        for (int m = 1; m < 16; m <<= 1) {
            r.x = fminf(r.x, __shfl_xor(r.x, m, 64));
            r.y = fminf(r.y, __shfl_xor(r.y, m, 64));
            r.z = fminf(r.z, __shfl_xor(r.z, m, 64));
            r.w = fminf(r.w, __shfl_xor(r.w, m, 64));
        }
        if (c < 4) {
            float v = (c == 0) ? r.x : (c == 1) ? r.y : (c == 2) ? r.z : r.w;
            rp[nt * 16 + q * 4 + c] = v;
        }
    }

    // ---- col partials: combine the 4 waves' colbuf slices ----
    __syncthreads();
    float* cp = colpart + (size_t)nch * TOTALQ + (size_t)b * NPTS
                        + (size_t)ms * MRANGE;
    for (int idx = threadIdx.x; idx < MRANGE; idx += BLK) {
        float m0 = fminf(colbuf[0][idx], colbuf[1][idx]);
        float m1 = fminf(colbuf[2][idx], colbuf[3][idx]);
        cp[idx] = fminf(m0, m1);
    }
}

__global__ __launch_bounds__(BLK) void chamfer_reduce_kernel(
        const float* __restrict__ rowpart, const float* __restrict__ colpart,
        float* __restrict__ out)
{
    int g = blockIdx.x * BLK + threadIdx.x;   // 0..65535
    int dir = g >> 15, i = g & (TOTALQ - 1);

    const float* part = dir ? colpart : rowpart;   // both: 16 slices x TOTALQ
    float m = part[i];
    #pragma unroll
    for (int s = 1; s < 16; ++s)
        m = fminf(m, part[(size_t)s * TOTALQ + i]);

    float acc = m * (1.0f / (float)TOTALQ);
    #pragma unroll
    for (int off = 32; off > 0; off >>= 1)
        acc += __shfl_down(acc, off, 64);
    __shared__ float wsum[BLK / 64];
    int lane = threadIdx.x & 63, wid = threadIdx.x >> 6;
    if (lane == 0) wsum[wid] = acc;
    __syncthreads();
    if (threadIdx.x == 0) {
        float s = 0.0f;
        #pragma unroll
        for (int wv = 0; wv < BLK / 64; ++wv) s += wsum[wv];
        atomicAdd(out, s);
    }
}

extern "C" void kernel_launch(void* const* d_in, const int* in_sizes, int n_in,
                              void* d_out, int out_size, void* d_ws, size_t ws_size,
                              hipStream_t stream) {
    const float* pred   = (const float*)d_in[0];
    const float* target = (const float*)d_in[1];
    float*       out    = (float*)d_out;

    ushort* packA   = (ushort*)d_ws;                                  // 2 MB
    ushort* packB   = packA + (size_t)TOTALQ * ROW_US;                // 2 MB
    float*  rowpart = (float*)((char*)d_ws + (size_t)4 * 1024 * 1024); // 2 MB
    float*  colpart = (float*)((char*)d_ws + (size_t)6 * 1024 * 1024); // 2 MB

    hipLaunchKernelGGL(chamfer_pack_kernel, dim3(2 * TOTALQ / BLK), dim3(BLK),
                       0, stream, pred, target, packA, packB, out);

    dim3 grid(BATCH * NCHUNKS, MSPLIT);       // 64 x 16 = 1024 blocks
    hipLaunchKernelGGL(chamfer_mfma_kernel, grid, dim3(BLK), 0, stream,
                       (const ushort*)packA, (const ushort*)packB,
                       rowpart, colpart);

    hipLaunchKernelGGL(chamfer_reduce_kernel, dim3(2 * TOTALQ / BLK), dim3(BLK),
                       0, stream, (const float*)rowpart, (const float*)colpart,
                       out);
}

// Round 8
// 103.661 us; speedup vs baseline: 1.0538x; 1.0538x over previous
//
#include <hip/hip_runtime.h>
#include <hip/hip_bf16.h>

// Chamfer distance, B=4, N=M=8192, D=3, fp32.
// R7: R6's one-pass col-min path was latency-poison (serial 8-deep colmin
// chain + 2 shuffles + LDS write per m-tile -> MfmaUtil 12%, VALUBusy 32%).
// MFMA is nearly free (2.1M mfma = ~4us of matrix pipe), so do TWO row-min
// passes (grid z = dir, A/B roles swapped). Loop body: 1 ds_read_b128 +
// 8 independent MFMA + 32 independent elementwise v_min. Zero cross-lane ops
// in the loop. Packed rows shrink to 32 B (K16..31 zero via zero fragments
// in quads 2-3). Numerics identical to R6 (verified absmax 0.0):
//   A row (query):  [-2h(3), -2l(3), -2h(3), n1,n2,n3, 1,1,1, 0]
//   B row (target): [ h(3),   h(3),   l(3),  1,1,1, n1,n2,n3, 0]
//   D[n][m] = ||q-t||^2 + O(l.l) ~ 1e-5
// ws (6 MB): pA_pred | pB_pred | pA_targ | pB_targ (1 MB each) | parts (2 MB)

typedef __attribute__((ext_vector_type(8))) short short8;
typedef __attribute__((ext_vector_type(4))) float f32x4;

#define BATCH 4
#define NPTS 8192
#define TOTALQ (BATCH * NPTS)   // 32768
#define BLK 256
#define WNT 8                   // 16-row tiles per wave -> 128 rows/wave
#define BROWS 512               // rows per block (4 waves)
#define NCH (TOTALQ / BROWS)    // 64 row-chunks (batch folded in)
#define MSPLIT 8                // col slices per batch
#define MRANGE (NPTS / MSPLIT)  // 1024 cols per block
#define MT_PER (MRANGE / 16)    // 64 m-tiles per block
#define ROW_US 16               // ushorts per packed row (32 B)

#define PACK_US ((size_t)TOTALQ * ROW_US)          // 1 MB per pack
#define PART_OFF ((size_t)4 * PACK_US * 2)         // bytes: 4 MB

__device__ __forceinline__ unsigned short f2bf(float f) {  // RTN-even
    unsigned int u = __float_as_uint(f);
    u += 0x7FFFu + ((u >> 16) & 1u);
    return (unsigned short)(u >> 16);
}
__device__ __forceinline__ float bf2f(unsigned short h) {
    return __uint_as_float(((unsigned int)h) << 16);
}
__device__ __forceinline__ unsigned int pk2(unsigned short a, unsigned short b) {
    return (unsigned int)a | ((unsigned int)b << 16);
}

__global__ __launch_bounds__(BLK) void chamfer_pack_kernel(
        const float* __restrict__ pred, const float* __restrict__ target,
        ushort* __restrict__ ws, float* __restrict__ out)
{
    int i = blockIdx.x * BLK + threadIdx.x;        // 0..65535
    if (i == 0) out[0] = 0.0f;                     // consumed 2 nodes later
    int which = i >> 15;                           // 0 = pred, 1 = target
    int p = i & (TOTALQ - 1);
    const float* src = which ? target : pred;
    float x = src[3 * p], y = src[3 * p + 1], z = src[3 * p + 2];

    unsigned short hx = f2bf(x), hy = f2bf(y), hz = f2bf(z);
    unsigned short lx = f2bf(x - bf2f(hx)), ly = f2bf(y - bf2f(hy)),
                   lz = f2bf(z - bf2f(hz));
    float nrm = fmaf(z, z, fmaf(y, y, x * x));
    unsigned short n1 = f2bf(nrm);
    float r1 = nrm - bf2f(n1);
    unsigned short n2 = f2bf(r1);
    unsigned short n3 = f2bf(r1 - bf2f(n2));
    const unsigned short ONE = 0x3F80;

    // -2*h, -2*l exact (power-of-2 scale of a bf16 value)
    unsigned short ax = f2bf(-2.f * bf2f(hx)), ay = f2bf(-2.f * bf2f(hy)),
                   az = f2bf(-2.f * bf2f(hz));
    unsigned short cx = f2bf(-2.f * bf2f(lx)), cy = f2bf(-2.f * bf2f(ly)),
                   cz = f2bf(-2.f * bf2f(lz));

    // A row k0..15: [ax,ay,az, cx,cy,cz, ax,ay,az, n1,n2,n3, 1,1,1, 0]
    uint4 A0 = { pk2(ax, ay), pk2(az, cx), pk2(cy, cz), pk2(ax, ay) };
    uint4 A1 = { pk2(az, n1), pk2(n2, n3), pk2(ONE, ONE), pk2(ONE, 0) };
    // B row k0..15: [hx,hy,hz, hx,hy,hz, lx,ly,lz, 1,1,1, n1,n2,n3, 0]
    uint4 B0 = { pk2(hx, hy), pk2(hz, hx), pk2(hy, hz), pk2(lx, ly) };
    uint4 B1 = { pk2(lz, ONE), pk2(ONE, ONE), pk2(n1, n2), pk2(n3, 0) };

    uint4* dA = (uint4*)(ws + (size_t)(2 * which) * PACK_US + (size_t)p * ROW_US);
    uint4* dB = (uint4*)(ws + (size_t)(2 * which + 1) * PACK_US + (size_t)p * ROW_US);
    dA[0] = A0;  dA[1] = A1;
    dB[0] = B0;  dB[1] = B1;
}

__global__ __launch_bounds__(BLK) void chamfer_mfma_kernel(
        const ushort* __restrict__ ws, float* __restrict__ part)
{
    const int dir = blockIdx.z;
    // dir0: A=pred, B=target ; dir1: A=target, B=pred
    const ushort* packA = ws + (dir ? 2 * PACK_US : 0);
    const ushort* packB = ws + (dir ? 1 * PACK_US : 3 * PACK_US);

    const int nch = blockIdx.x;           // 0..63  (row chunk, batch folded in)
    const int b   = nch >> 4;             // batch of these rows
    const int ms  = blockIdx.y;           // 0..7   (col slice within batch)
    const int w    = threadIdx.x >> 6;
    const int lane = threadIdx.x & 63;
    const int c = lane & 15, q = lane >> 4;

    __shared__ uint4 ldsb[MRANGE * 2];    // 1024 B-rows x 32 B = 32 KB

    const short8 zero8 = (short8){0, 0, 0, 0, 0, 0, 0, 0};
    const f32x4  zacc  = (f32x4){0.f, 0.f, 0.f, 0.f};

    // ---- stage B rows (flat contiguous copy, coalesced) ----
    {
        const uint4* gB = (const uint4*)(packB +
            ((size_t)b * NPTS + (size_t)ms * MRANGE) * ROW_US);
        #pragma unroll
        for (int r = threadIdx.x; r < MRANGE * 2; r += BLK)
            ldsb[r] = gB[r];
    }

    // ---- A fragments: lane holds row (rowstart + nt*16 + c), k = 8q..8q+7;
    //      quads 2-3 are the implicit zero half (k16..31) ----
    const int rowstart = nch * BROWS + w * (WNT * 16);   // global row id
    short8 afrag[WNT];
    #pragma unroll
    for (int nt = 0; nt < WNT; ++nt) {
        afrag[nt] = (q < 2)
            ? *(const short8*)(packA + (size_t)(rowstart + nt * 16 + c) * ROW_US + 8 * q)
            : zero8;
    }

    f32x4 rowacc[WNT];
    #pragma unroll
    for (int nt = 0; nt < WNT; ++nt)
        rowacc[nt] = (f32x4){3.4e38f, 3.4e38f, 3.4e38f, 3.4e38f};

    __syncthreads();

    // ---- main loop: 1 ds_read_b128 + 8 MFMA + 32 elementwise v_min ----
    #pragma unroll 2
    for (int mt = 0; mt < MT_PER; ++mt) {
        short8 bfrag = (q < 2)
            ? *(const short8*)&ldsb[(mt * 16 + c) * 2 + q]
            : zero8;
        #pragma unroll
        for (int nt = 0; nt < WNT; ++nt) {
            f32x4 d = __builtin_amdgcn_mfma_f32_16x16x32_bf16(
                          afrag[nt], bfrag, zacc, 0, 0, 0);
            rowacc[nt].x = fminf(rowacc[nt].x, d.x);
            rowacc[nt].y = fminf(rowacc[nt].y, d.y);
            rowacc[nt].z = fminf(rowacc[nt].z, d.z);
            rowacc[nt].w = fminf(rowacc[nt].w, d.w);
        }
    }

    // ---- epilogue: fold the 16 col-lanes; store row partials ----
    // C layout: col = lane&15, row = q*4 + reg (m89)
    float* rp = part + (size_t)(dir * MSPLIT + ms) * TOTALQ + rowstart;
    #pragma unroll
    for (int nt = 0; nt < WNT; ++nt) {
        f32x4 r = rowacc[nt];
        #pragma unroll
        for (int m = 1; m < 16; m <<= 1) {
            r.x = fminf(r.x, __shfl_xor(r.x, m, 64));
            r.y = fminf(r.y, __shfl_xor(r.y, m, 64));
            r.z = fminf(r.z, __shfl_xor(r.z, m, 64));
            r.w = fminf(r.w, __shfl_xor(r.w, m, 64));
        }
        if (c < 4) {
            float v = (c == 0) ? r.x : (c == 1) ? r.y : (c == 2) ? r.z : r.w;
            rp[nt * 16 + q * 4 + c] = v;
        }
    }
}

__global__ __launch_bounds__(BLK) void chamfer_reduce_kernel(
        const float* __restrict__ part, float* __restrict__ out)
{
    int g = blockIdx.x * BLK + threadIdx.x;   // 0..65535
    int dir = g >> 15, i = g & (TOTALQ - 1);

    const float* p = part + (size_t)dir * MSPLIT * TOTALQ + i;
    float m = p[0];
    #pragma unroll
    for (int s = 1; s < MSPLIT; ++s)
        m = fminf(m, p[(size_t)s * TOTALQ]);

    float acc = m * (1.0f / (float)TOTALQ);
    #pragma unroll
    for (int off = 32; off > 0; off >>= 1)
        acc += __shfl_down(acc, off, 64);
    __shared__ float wsum[BLK / 64];
    int lane = threadIdx.x & 63, wid = threadIdx.x >> 6;
    if (lane == 0) wsum[wid] = acc;
    __syncthreads();
    if (threadIdx.x == 0) {
        float s = 0.0f;
        #pragma unroll
        for (int wv = 0; wv < BLK / 64; ++wv) s += wsum[wv];
        atomicAdd(out, s);
    }
}

extern "C" void kernel_launch(void* const* d_in, const int* in_sizes, int n_in,
                              void* d_out, int out_size, void* d_ws, size_t ws_size,
                              hipStream_t stream) {
    const float* pred   = (const float*)d_in[0];
    const float* target = (const float*)d_in[1];
    float*       out    = (float*)d_out;
    ushort*      wsp    = (ushort*)d_ws;                      // packs: 4 MB
    float*       part   = (float*)((char*)d_ws + PART_OFF);   // partials: 2 MB

    hipLaunchKernelGGL(chamfer_pack_kernel, dim3(2 * TOTALQ / BLK), dim3(BLK),
                       0, stream, pred, target, wsp, out);

    dim3 grid(NCH, MSPLIT, 2);                // 64 x 8 x 2 = 1024 blocks
    hipLaunchKernelGGL(chamfer_mfma_kernel, grid, dim3(BLK), 0, stream,
                       (const ushort*)wsp, part);

    hipLaunchKernelGGL(chamfer_reduce_kernel, dim3(2 * TOTALQ / BLK), dim3(BLK),
                       0, stream, (const float*)part, out);
}

// Round 9
// 95.584 us; speedup vs baseline: 1.1428x; 1.0845x over previous
//
#include <hip/hip_runtime.h>
#include <hip/hip_bf16.h>

// Chamfer distance, B=4, N=M=8192, D=3, fp32.
// R8: 32x32x16 MFMA — the 15-slot split-bf16 payload EXACTLY fits K=16:
// no zero K-half (R7 wasted 50% of each MFMA), no divergent frag reads,
// 1024 pairs per MFMA, 4x fewer ds_reads per pair. Packs byte-identical to
// R7's (absmax 0.0 verified). min3 folds TWO m-tiles per VALU op ->
// 1 VALU per 128 pairs. C/D layout (m74/m101): col=lane&31,
// row=(reg&3)+8*(reg>>2)+4*(lane>>5). A/B frag: row/col=lane&31,
// k=(lane>>5)*8+j. Split-half LDS regions keep bfrag reads conflict-free.

typedef __attribute__((ext_vector_type(8)))  short short8;
typedef __attribute__((ext_vector_type(16))) float f32x16;

#define BATCH 4
#define NPTS 8192
#define TOTALQ (BATCH * NPTS)   // 32768
#define BLK 256
#define WNT 2                   // 32-row tiles per wave -> 64 rows/wave
#define BROWS 256               // rows per block (4 waves)
#define NCH (TOTALQ / BROWS)    // 128 row chunks (batch folded in)
#define MSPLIT 8                // col slices per batch
#define MRANGE (NPTS / MSPLIT)  // 1024 cols per block
#define MT_PER (MRANGE / 32)    // 32 m-tiles per block
#define ROW_US 16               // ushorts per packed row (32 B)

#define PACK_US ((size_t)TOTALQ * ROW_US)   // 1 MB per pack
#define PART_OFF ((size_t)4 * PACK_US * 2)  // bytes: 4 MB

__device__ __forceinline__ unsigned short f2bf(float f) {  // RTN-even
    unsigned int u = __float_as_uint(f);
    u += 0x7FFFu + ((u >> 16) & 1u);
    return (unsigned short)(u >> 16);
}
__device__ __forceinline__ float bf2f(unsigned short h) {
    return __uint_as_float(((unsigned int)h) << 16);
}
__device__ __forceinline__ unsigned int pk2(unsigned short a, unsigned short b) {
    return (unsigned int)a | ((unsigned int)b << 16);
}

__global__ __launch_bounds__(BLK) void chamfer_pack_kernel(
        const float* __restrict__ pred, const float* __restrict__ target,
        ushort* __restrict__ ws, float* __restrict__ out)
{
    int i = blockIdx.x * BLK + threadIdx.x;        // 0..65535
    if (i == 0) out[0] = 0.0f;                     // consumed 2 nodes later
    int which = i >> 15;                           // 0 = pred, 1 = target
    int p = i & (TOTALQ - 1);
    const float* src = which ? target : pred;
    float x = src[3 * p], y = src[3 * p + 1], z = src[3 * p + 2];

    unsigned short hx = f2bf(x), hy = f2bf(y), hz = f2bf(z);
    unsigned short lx = f2bf(x - bf2f(hx)), ly = f2bf(y - bf2f(hy)),
                   lz = f2bf(z - bf2f(hz));
    float nrm = fmaf(z, z, fmaf(y, y, x * x));
    unsigned short n1 = f2bf(nrm);
    float r1 = nrm - bf2f(n1);
    unsigned short n2 = f2bf(r1);
    unsigned short n3 = f2bf(r1 - bf2f(n2));
    const unsigned short ONE = 0x3F80;

    unsigned short ax = f2bf(-2.f * bf2f(hx)), ay = f2bf(-2.f * bf2f(hy)),
                   az = f2bf(-2.f * bf2f(hz));
    unsigned short cx = f2bf(-2.f * bf2f(lx)), cy = f2bf(-2.f * bf2f(ly)),
                   cz = f2bf(-2.f * bf2f(lz));

    // k0..15 pairing (A x B): -2h.h | -2l.h | -2h.l | pn.1 | 1.tn | 0
    uint4 A0 = { pk2(ax, ay), pk2(az, cx), pk2(cy, cz), pk2(ax, ay) };
    uint4 A1 = { pk2(az, n1), pk2(n2, n3), pk2(ONE, ONE), pk2(ONE, 0) };
    uint4 B0 = { pk2(hx, hy), pk2(hz, hx), pk2(hy, hz), pk2(lx, ly) };
    uint4 B1 = { pk2(lz, ONE), pk2(ONE, ONE), pk2(n1, n2), pk2(n3, 0) };

    uint4* dA = (uint4*)(ws + (size_t)(2 * which) * PACK_US + (size_t)p * ROW_US);
    uint4* dB = (uint4*)(ws + (size_t)(2 * which + 1) * PACK_US + (size_t)p * ROW_US);
    dA[0] = A0;  dA[1] = A1;
    dB[0] = B0;  dB[1] = B1;
}

__global__ __launch_bounds__(BLK) void chamfer_mfma_kernel(
        const ushort* __restrict__ ws, float* __restrict__ part)
{
    const int dir = blockIdx.z;
    // dir0: A=pred, B=target ; dir1: A=target, B=pred
    const ushort* packA = ws + (dir ? 2 * PACK_US : 0);
    const ushort* packB = ws + (dir ? 1 * PACK_US : 3 * PACK_US);

    const int nch = blockIdx.x;           // 0..127 (row chunk, batch folded in)
    const int b   = nch >> 5;             // 32 chunks per batch
    const int ms  = blockIdx.y;           // 0..7   (col slice within batch)
    const int w    = threadIdx.x >> 6;
    const int lane = threadIdx.x & 63;
    const int c = lane & 31;              // row (A) / col (B) within tile
    const int g = lane >> 5;              // k-half

    // split-half layout: half g of row r at ushort offset g*8192 + r*8
    __shared__ uint4 ldsb[2][MRANGE];     // 32 KB

    // ---- stage B rows (each thread: 32 B contiguous read, 2 region writes) ----
    {
        const uint4* gB = (const uint4*)(packB +
            ((size_t)b * NPTS + (size_t)ms * MRANGE) * ROW_US);
        #pragma unroll
        for (int r = threadIdx.x; r < MRANGE; r += BLK) {
            ldsb[0][r] = gB[2 * r];
            ldsb[1][r] = gB[2 * r + 1];
        }
    }

    // ---- A fragments: row = rowstart + nt*32 + c, k-half g ----
    const int rowstart = nch * BROWS + w * (WNT * 32);   // global row id
    short8 afrag[WNT];
    #pragma unroll
    for (int nt = 0; nt < WNT; ++nt) {
        afrag[nt] = *(const short8*)(
            packA + (size_t)(rowstart + nt * 32 + c) * ROW_US + 8 * g);
    }

    f32x16 acc[WNT];
    #pragma unroll
    for (int nt = 0; nt < WNT; ++nt)
        #pragma unroll
        for (int r = 0; r < 16; ++r)
            acc[nt][r] = 3.4e38f;
    const f32x16 zacc = (f32x16)(0.f);

    __syncthreads();

    const ushort* ldsu = (const ushort*)ldsb;

    // ---- main loop: 2 ds_read_b128 + 4 MFMA + 32 min3 per 2 m-tiles ----
    #pragma unroll 4
    for (int mt = 0; mt < MT_PER; mt += 2) {
        short8 bf0 = *(const short8*)(ldsu + g * (MRANGE * 8) + (mt * 32 + c) * 8);
        short8 bf1 = *(const short8*)(ldsu + g * (MRANGE * 8) + ((mt + 1) * 32 + c) * 8);
        #pragma unroll
        for (int nt = 0; nt < WNT; ++nt) {
            f32x16 d0 = __builtin_amdgcn_mfma_f32_32x32x16_bf16(
                            afrag[nt], bf0, zacc, 0, 0, 0);
            f32x16 d1 = __builtin_amdgcn_mfma_f32_32x32x16_bf16(
                            afrag[nt], bf1, zacc, 0, 0, 0);
            #pragma unroll
            for (int r = 0; r < 16; ++r)
                acc[nt][r] = fminf(fminf(acc[nt][r], d0[r]), d1[r]);  // v_min3
        }
    }

    // ---- epilogue: fold 32 cols (xor within 32-lane group), store rows ----
    float* rp = part + (size_t)(dir * MSPLIT + ms) * TOTALQ + rowstart;
    #pragma unroll
    for (int nt = 0; nt < WNT; ++nt) {
        f32x16 v = acc[nt];
        #pragma unroll
        for (int m = 1; m < 32; m <<= 1) {
            #pragma unroll
            for (int r = 0; r < 16; ++r)
                v[r] = fminf(v[r], __shfl_xor(v[r], m, 64));
        }
        #pragma unroll
        for (int r = 0; r < 16; ++r) {
            int row = (r & 3) + 8 * (r >> 2) + 4 * g;   // C/D row map (m74/m101)
            if (c == r) rp[nt * 32 + row] = v[r];
        }
    }
}

__global__ __launch_bounds__(BLK) void chamfer_reduce_kernel(
        const float* __restrict__ part, float* __restrict__ out)
{
    int gl = blockIdx.x * BLK + threadIdx.x;   // 0..65535
    int dir = gl >> 15, i = gl & (TOTALQ - 1);

    const float* p = part + (size_t)dir * MSPLIT * TOTALQ + i;
    float m = p[0];
    #pragma unroll
    for (int s = 1; s < MSPLIT; ++s)
        m = fminf(m, p[(size_t)s * TOTALQ]);

    float acc = m * (1.0f / (float)TOTALQ);
    #pragma unroll
    for (int off = 32; off > 0; off >>= 1)
        acc += __shfl_down(acc, off, 64);
    __shared__ float wsum[BLK / 64];
    int lane = threadIdx.x & 63, wid = threadIdx.x >> 6;
    if (lane == 0) wsum[wid] = acc;
    __syncthreads();
    if (threadIdx.x == 0) {
        float s = 0.0f;
        #pragma unroll
        for (int wv = 0; wv < BLK / 64; ++wv) s += wsum[wv];
        atomicAdd(out, s);
    }
}

extern "C" void kernel_launch(void* const* d_in, const int* in_sizes, int n_in,
                              void* d_out, int out_size, void* d_ws, size_t ws_size,
                              hipStream_t stream) {
    const float* pred   = (const float*)d_in[0];
    const float* target = (const float*)d_in[1];
    float*       out    = (float*)d_out;
    ushort*      wsp    = (ushort*)d_ws;                      // packs: 4 MB
    float*       part   = (float*)((char*)d_ws + PART_OFF);   // partials: 2 MB

    hipLaunchKernelGGL(chamfer_pack_kernel, dim3(2 * TOTALQ / BLK), dim3(BLK),
                       0, stream, pred, target, wsp, out);

    dim3 grid(NCH, MSPLIT, 2);                // 128 x 8 x 2 = 2048 blocks
    hipLaunchKernelGGL(chamfer_mfma_kernel, grid, dim3(BLK), 0, stream,
                       (const ushort*)wsp, part);

    hipLaunchKernelGGL(chamfer_reduce_kernel, dim3(2 * TOTALQ / BLK), dim3(BLK),
                       0, stream, (const float*)part, out);
}